// Round 13
// baseline (247.966 us; speedup 1.0000x reference)
//
#include <hip/hip_runtime.h>
#include <math.h>

#define N_NODES 50000
#define N_EDGES 800000
#define EP (N_EDGES + N_NODES)   // edges incl. self loops
#define NEG_SLOPE 0.2f
#define SCAN_BLOCKS ((N_NODES + 255) / 256)   // 196

typedef __attribute__((ext_vector_type(8))) short bf16x8;
typedef __attribute__((ext_vector_type(4))) float f32x4;

// ---------- helpers ----------
__device__ __forceinline__ unsigned short f2bf(float f) {
  unsigned u = __float_as_uint(f);
  unsigned r = (u + 0x7FFFu + ((u >> 16) & 1u)) >> 16;
  return (unsigned short)r;
}
__device__ __forceinline__ float bf2f(unsigned short b) {
  return __uint_as_float(((unsigned)b) << 16);
}

__global__ void fill_u32(unsigned* p, unsigned v, int n) {
  int i = blockIdx.x * blockDim.x + threadIdx.x;
  if (i < n) p[i] = v;
}

// ---------- pass 1: per-dst rank via the ONLY atomic pass ----------
__global__ void rank_pass(const int* __restrict__ ei, int* __restrict__ cnt,
                          int* __restrict__ rank) {
  int e = blockIdx.x * blockDim.x + threadIdx.x;
  if (e >= N_EDGES) return;
  rank[e] = atomicAdd(&cnt[ei[N_EDGES + e]], 1);
}

// ---------- block sums of (cnt+1) ----------
__global__ void block_sums(const int* __restrict__ cnt, int* __restrict__ bsum) {
  __shared__ int ws[4];
  int b = blockIdx.x;
  int i = b * 256 + threadIdx.x;
  int v = (i < N_NODES) ? (cnt[i] + 1) : 0;   // +1 = self loop
  #pragma unroll
  for (int off = 32; off > 0; off >>= 1) v += __shfl_down(v, off);
  if ((threadIdx.x & 63) == 0) ws[threadIdx.x >> 6] = v;
  __syncthreads();
  if (threadIdx.x == 0) bsum[b] = ws[0] + ws[1] + ws[2] + ws[3];
}

// ---------- rowptr emit with fused top-level scan (each block scans bsum) --------
__global__ void emit_rowptr(const int* __restrict__ cnt, const int* __restrict__ bsum,
                            int* __restrict__ rowptr) {
  __shared__ int buf[2][256];
  int b = blockIdx.x, t = threadIdx.x;
  int vb = (t < SCAN_BLOCKS) ? bsum[t] : 0;
  buf[0][t] = vb;
  __syncthreads();
  int cur = 0;
  for (int off = 1; off < 256; off <<= 1) {
    int x = buf[cur][t];
    if (t >= off) x += buf[cur][t - off];
    buf[cur ^ 1][t] = x;
    cur ^= 1;
    __syncthreads();
  }
  int base = buf[cur][b] - ((b < SCAN_BLOCKS) ? bsum[b] : 0);  // exclusive prefix
  __syncthreads();
  int i = b * 256 + t;
  int v = (i < N_NODES) ? (cnt[i] + 1) : 0;
  buf[cur][t] = v;
  __syncthreads();
  int c2 = cur;
  for (int off = 1; off < 256; off <<= 1) {
    int x = buf[c2][t];
    if (t >= off) x += buf[c2][t - off];
    buf[c2 ^ 1][t] = x;
    c2 ^= 1;
    __syncthreads();
  }
  int incl = buf[c2][t];
  if (i < N_NODES) {
    rowptr[i] = base + incl - v;
    if (i == N_NODES - 1) rowptr[N_NODES] = base + incl;
  }
}

// ---------- pass 2: computed scatter (NO atomics); self-loop slot = end-1 ----------
__global__ void scatter_pass(const int* __restrict__ ei, const float* __restrict__ ea,
                             const int* __restrict__ rowptr, const int* __restrict__ rank,
                             uint2* __restrict__ ecsr) {
  int e = blockIdx.x * blockDim.x + threadIdx.x;
  if (e >= N_EDGES) return;
  int d = ei[N_EDGES + e];
  int pos = rowptr[d] + rank[e];
  uint2 v;
  v.x = (unsigned)ei[e];
  v.y = (unsigned)f2bf(ea[2 * e]) | ((unsigned)f2bf(ea[2 * e + 1]) << 16);
  ecsr[pos] = v;
}

// ---------- fused misc prep: lattr_fin + bt_split + prep_ae (role by blockIdx) ----
#define MISC_LATTR 196
#define MISC_BT    384
__global__ void prep_misc(const int* __restrict__ rowptr, uint2* __restrict__ ecsr,
                          const float* __restrict__ W1, const float* __restrict__ W2,
                          unsigned short* __restrict__ b1h, unsigned short* __restrict__ b1l,
                          unsigned short* __restrict__ b2h, unsigned short* __restrict__ b2l,
                          const float* __restrict__ ae1, const float* __restrict__ ae2,
                          const float* __restrict__ We1, const float* __restrict__ We2,
                          float* __restrict__ Ae) {
  int b = blockIdx.x;
  int t = threadIdx.x;
  if (b < MISC_LATTR) {
    // self-loop attr = mean of incoming ea; record at segment end-1
    int n = b * 256 + t;
    if (n >= N_NODES) return;
    int beg = rowptr[n], end = rowptr[n + 1];
    float s0 = 0.f, s1 = 0.f;
    for (int j = beg; j < end - 1; ++j) {
      unsigned p = ecsr[j].y;
      s0 += __uint_as_float(p << 16);
      s1 += __uint_as_float(p & 0xFFFF0000u);
    }
    float c = fmaxf((float)(end - 1 - beg), 1.0f);
    uint2 m;
    m.x = (unsigned)n;
    m.y = (unsigned)f2bf(s0 / c) | ((unsigned)f2bf(s1 / c) << 16);
    ecsr[end - 1] = m;
  } else if (b < MISC_LATTR + MISC_BT) {
    // W -> W^T hi/lo split
    int nb = b - MISC_LATTR;
    float v; unsigned short* ph; unsigned short* pl; int idx;
    if (nb < 256) { v = W1[t * 256 + nb];         ph = b1h; pl = b1l; idx = nb * 256 + t; }
    else          { v = W2[t * 128 + (nb - 256)]; ph = b2h; pl = b2l; idx = (nb - 256) * 256 + t; }
    unsigned short h = f2bf(v);
    ph[idx] = h;
    pl[idx] = f2bf(v - bf2f(h));
  } else {
    // Ae[d][h] = sum_c We[d, h*128+c] * att_e[h,c]
    if (t >= 64) return;
    int bb = b - (MISC_LATTR + MISC_BT);   // 0..5
    float s = 0.f;
    if (bb < 4) {
      int d = bb >> 1, h = bb & 1;
      for (int c = t; c < 128; c += 64)
        s += We1[d * 256 + h * 128 + c] * ae1[h * 128 + c];
    } else {
      int d = bb - 4;
      for (int c = t; c < 128; c += 64)
        s += We2[d * 128 + c] * ae2[c];
    }
    for (int off = 32; off > 0; off >>= 1) s += __shfl_down(s, off);
    if (t == 0) Ae[bb] = s;  // [d0h0, d0h1, d1h0, d1h1, d0(conv2), d1(conv2)]
  }
}

// ---------- split-bf16 MFMA GEMM (fp32-accurate) with fused attention epilogue ----
template <int H>
__global__ __launch_bounds__(256) void gemm_split(
    const float* __restrict__ A,
    const unsigned short* __restrict__ Bth, const unsigned short* __restrict__ Btl,
    unsigned short* __restrict__ C, int M, int N,
    const float* __restrict__ att_src, const float* __restrict__ att_dst,
    float* __restrict__ asrc, float* __restrict__ adst) {
  __shared__ __attribute__((aligned(16))) unsigned short As[2][64][40];
  __shared__ __attribute__((aligned(16))) unsigned short Bs[2][128][40];
  __shared__ float redS[2][64], redD[2][64];   // [wc][row_local]
  int bm = blockIdx.y * 64, bn = blockIdx.x * 128;
  int tid = threadIdx.x;
  int l = tid & 63;
  int wid = tid >> 6;
  int wr = wid >> 1, wc = wid & 1;
  int rr = l & 15, kc = l >> 4;

  f32x4 acc[2][4];
  #pragma unroll
  for (int i = 0; i < 2; ++i)
    #pragma unroll
    for (int j = 0; j < 4; ++j)
      acc[i][j] = (f32x4){0.f, 0.f, 0.f, 0.f};

  int ar = tid >> 2, ac = tid & 3;
  int gm = bm + ar;

  for (int kt = 0; kt < 8; ++kt) {
    int k0 = kt * 32;
    float4 f0 = {0.f, 0.f, 0.f, 0.f}, f1 = f0;
    if (gm < M) {
      f0 = *(const float4*)(A + (size_t)gm * 256 + k0 + ac * 8);
      f1 = *(const float4*)(A + (size_t)gm * 256 + k0 + ac * 8 + 4);
    }
    float f[8] = {f0.x, f0.y, f0.z, f0.w, f1.x, f1.y, f1.z, f1.w};
    unsigned hw[4], lw[4];
    #pragma unroll
    for (int q = 0; q < 4; ++q) {
      unsigned short ha = f2bf(f[2 * q]),  hb = f2bf(f[2 * q + 1]);
      unsigned short la = f2bf(f[2 * q] - bf2f(ha)), lb = f2bf(f[2 * q + 1] - bf2f(hb));
      hw[q] = (unsigned)ha | ((unsigned)hb << 16);
      lw[q] = (unsigned)la | ((unsigned)lb << 16);
    }
    *(uint4*)&As[0][ar][ac * 8] = make_uint4(hw[0], hw[1], hw[2], hw[3]);
    *(uint4*)&As[1][ar][ac * 8] = make_uint4(lw[0], lw[1], lw[2], lw[3]);
    #pragma unroll
    for (int p = 0; p < 2; ++p) {
      int id = tid + p * 256;
      int nn = id >> 2, cc = id & 3;
      *(uint4*)&Bs[0][nn][cc * 8] = *(const uint4*)(Bth + (size_t)(bn + nn) * 256 + k0 + cc * 8);
      *(uint4*)&Bs[1][nn][cc * 8] = *(const uint4*)(Btl + (size_t)(bn + nn) * 256 + k0 + cc * 8);
    }
    __syncthreads();
    bf16x8 ah[2], alo[2], bh[4], bl[4];
    #pragma unroll
    for (int i = 0; i < 2; ++i) {
      ah[i]  = *(const bf16x8*)&As[0][wr * 32 + i * 16 + rr][kc * 8];
      alo[i] = *(const bf16x8*)&As[1][wr * 32 + i * 16 + rr][kc * 8];
    }
    #pragma unroll
    for (int j = 0; j < 4; ++j) {
      bh[j] = *(const bf16x8*)&Bs[0][wc * 64 + j * 16 + rr][kc * 8];
      bl[j] = *(const bf16x8*)&Bs[1][wc * 64 + j * 16 + rr][kc * 8];
    }
    #pragma unroll
    for (int i = 0; i < 2; ++i)
      #pragma unroll
      for (int j = 0; j < 4; ++j) {
        acc[i][j] = __builtin_amdgcn_mfma_f32_16x16x32_bf16(ah[i],  bh[j], acc[i][j], 0, 0, 0);
        acc[i][j] = __builtin_amdgcn_mfma_f32_16x16x32_bf16(ah[i],  bl[j], acc[i][j], 0, 0, 0);
        acc[i][j] = __builtin_amdgcn_mfma_f32_16x16x32_bf16(alo[i], bh[j], acc[i][j], 0, 0, 0);
      }
    __syncthreads();
  }

  // C store (bf16)
  #pragma unroll
  for (int i = 0; i < 2; ++i)
    #pragma unroll
    for (int reg = 0; reg < 4; ++reg) {
      int row = bm + wr * 32 + i * 16 + kc * 4 + reg;
      if (row < M) {
        #pragma unroll
        for (int j = 0; j < 4; ++j) {
          int col = bn + wc * 64 + j * 16 + rr;
          C[(size_t)row * N + col] = f2bf(acc[i][j][reg]);
        }
      }
    }

  // fused attention dot products: per-wave partials -> LDS -> direct store
  int head = (H == 2) ? (bn >> 7) : 0;
  float ats[4], atd[4];
  #pragma unroll
  for (int j = 0; j < 4; ++j) {
    int colh = wc * 64 + j * 16 + rr;
    ats[j] = att_src[head * 128 + colh];
    atd[j] = att_dst[head * 128 + colh];
  }
  #pragma unroll
  for (int i = 0; i < 2; ++i)
    #pragma unroll
    for (int reg = 0; reg < 4; ++reg) {
      float sp = acc[i][0][reg] * ats[0] + acc[i][1][reg] * ats[1] +
                 acc[i][2][reg] * ats[2] + acc[i][3][reg] * ats[3];
      float dp = acc[i][0][reg] * atd[0] + acc[i][1][reg] * atd[1] +
                 acc[i][2][reg] * atd[2] + acc[i][3][reg] * atd[3];
      #pragma unroll
      for (int off = 1; off < 16; off <<= 1) {
        sp += __shfl_xor(sp, off);
        dp += __shfl_xor(dp, off);
      }
      if (rr == 0) {
        int row_local = wr * 32 + i * 16 + kc * 4 + reg;
        redS[wc][row_local] = sp;
        redD[wc][row_local] = dp;
      }
    }
  __syncthreads();
  if (tid < 64) {
    int row = bm + tid;
    if (row < M) {
      asrc[row * H + head] = redS[0][tid] + redS[1][tid];
      adst[row * H + head] = redD[0][tid] + redD[1][tid];
    }
  }
}

// ---------- fused aggregation: 4 waves/block, ONE NODE PER WAVE, wave-sync LDS -----
// Each wave owns a private LDS slice; no __syncthreads (per-wave DS ops are in-order;
// asm lgkmcnt fence + sched_barrier orders phase A writes before phase B reads).
template <int H, int ACT>
__global__ __launch_bounds__(256)
void aggregate_fused(const unsigned short* __restrict__ xh, const float* __restrict__ asrc,
                     const float* __restrict__ adst, const uint2* __restrict__ ecsr,
                     const int* __restrict__ rowptr,
                     const float* __restrict__ Ae, int aeoff,
                     const float* __restrict__ bias, float* __restrict__ out) {
  constexpr int D = H * 128;
  constexpr int COLS = D / 64;       // 4 (conv1) or 2 (conv2)
  __shared__ float exl[4][256][H];
  __shared__ int sl[4][256];
  int wid = threadIdx.x >> 6;
  int t = threadIdx.x & 63;          // lane
  int n = blockIdx.x * 4 + wid;
  if (n >= N_NODES) return;
  int beg = rowptr[n], end = rowptr[n + 1];
  int hA = t & (H - 1);              // phase-A head (fixed per lane)
  float adnA = adst[n * H + hA];
  float Ae0 = Ae[aeoff + hA], Ae1 = Ae[aeoff + H + hA];
  int hB = (H == 2) ? (t >> 5) : 0;  // phase-B head (cols COLS*t..COLS*t+COLS-1)
  float lsum = 0.f;
  float acc[4][COLS];
  #pragma unroll
  for (int q = 0; q < 4; ++q)
    #pragma unroll
    for (int c = 0; c < COLS; ++c) acc[q][c] = 0.f;

  for (int cbeg = beg; cbeg < end; cbeg += 256) {
    int cnt = min(256, end - cbeg);
    for (int idx = t; idx < cnt * H; idx += 64) {
      int j0 = (H == 2) ? (idx >> 1) : idx;
      uint2 ev = ecsr[cbeg + j0];
      int s = (int)ev.x;
      float ea0 = __uint_as_float(ev.y << 16);
      float ea1 = __uint_as_float(ev.y & 0xFFFF0000u);
      float lg = asrc[s * H + hA] + adnA + ea0 * Ae0 + ea1 * Ae1;
      lg = (lg > 0.f) ? lg : NEG_SLOPE * lg;
      float ex = __expf(lg);
      exl[wid][j0][hA] = ex;
      if (hA == 0) sl[wid][j0] = s;
      lsum += ex;
    }
    // wave-sync: drain LDS writes, pin ordering (rule #18 fence)
    asm volatile("s_waitcnt lgkmcnt(0)" ::: "memory");
    __builtin_amdgcn_sched_barrier(0);
    int j = 0;
    for (; j + 8 <= cnt; j += 8) {
      #pragma unroll
      for (int q = 0; q < 8; ++q) {
        float e = exl[wid][j + q][hB];
        int s = sl[wid][j + q];
        if (COLS == 4) {
          uint2 u = *(const uint2*)(xh + (size_t)s * D + 4 * t);
          acc[q & 3][0] = fmaf(e, __uint_as_float(u.x << 16), acc[q & 3][0]);
          acc[q & 3][1] = fmaf(e, __uint_as_float(u.x & 0xFFFF0000u), acc[q & 3][1]);
          acc[q & 3][2] = fmaf(e, __uint_as_float(u.y << 16), acc[q & 3][2]);
          acc[q & 3][3] = fmaf(e, __uint_as_float(u.y & 0xFFFF0000u), acc[q & 3][3]);
        } else {
          unsigned u = *(const unsigned*)(xh + (size_t)s * D + 2 * t);
          acc[q & 3][0] = fmaf(e, __uint_as_float(u << 16), acc[q & 3][0]);
          acc[q & 3][1] = fmaf(e, __uint_as_float(u & 0xFFFF0000u), acc[q & 3][1]);
        }
      }
    }
    for (; j < cnt; ++j) {
      float e = exl[wid][j][hB];
      int s = sl[wid][j];
      if (COLS == 4) {
        uint2 u = *(const uint2*)(xh + (size_t)s * D + 4 * t);
        acc[0][0] = fmaf(e, __uint_as_float(u.x << 16), acc[0][0]);
        acc[0][1] = fmaf(e, __uint_as_float(u.x & 0xFFFF0000u), acc[0][1]);
        acc[0][2] = fmaf(e, __uint_as_float(u.y << 16), acc[0][2]);
        acc[0][3] = fmaf(e, __uint_as_float(u.y & 0xFFFF0000u), acc[0][3]);
      } else {
        unsigned u = *(const unsigned*)(xh + (size_t)s * D + 2 * t);
        acc[0][0] = fmaf(e, __uint_as_float(u << 16), acc[0][0]);
        acc[0][1] = fmaf(e, __uint_as_float(u & 0xFFFF0000u), acc[0][1]);
      }
    }
    asm volatile("" ::: "memory");   // WAR fence before next chunk's phase A
  }

  // wave-only reduction of lsum per head-parity class
  #pragma unroll
  for (int off = H; off < 64; off <<= 1) lsum += __shfl_xor(lsum, off);
  float tot = (H == 2) ? __shfl(lsum, hB) : lsum;
  float inv = 1.0f / (tot + 1e-16f);

  float v[COLS];
  #pragma unroll
  for (int c = 0; c < COLS; ++c) {
    v[c] = fmaf(inv, (acc[0][c] + acc[1][c]) + (acc[2][c] + acc[3][c]),
                bias[COLS * t + c]);
    if (ACT) v[c] = (v[c] > 0.f) ? v[c] : expm1f(v[c]);
  }
  if (COLS == 4) {
    *(float4*)(out + (size_t)n * D + 4 * t) = make_float4(v[0], v[1], v[2], v[3]);
  } else {
    *(float2*)(out + (size_t)n * D + 2 * t) = make_float2(v[0], v[1]);
  }
}

// ---------- launch ----------
extern "C" void kernel_launch(void* const* d_in, const int* in_sizes, int n_in,
                              void* d_out, int out_size, void* d_ws, size_t ws_size,
                              hipStream_t stream) {
  const float* x    = (const float*)d_in[0];
  const int*   ei   = (const int*)d_in[1];
  const float* ea   = (const float*)d_in[2];
  const float* W1   = (const float*)d_in[3];
  const float* as1  = (const float*)d_in[4];
  const float* ad1  = (const float*)d_in[5];
  const float* We1  = (const float*)d_in[6];
  const float* ae1  = (const float*)d_in[7];
  const float* b1   = (const float*)d_in[8];
  const float* W2   = (const float*)d_in[9];
  const float* as2  = (const float*)d_in[10];
  const float* ad2  = (const float*)d_in[11];
  const float* We2  = (const float*)d_in[12];
  const float* ae2  = (const float*)d_in[13];
  const float* b2   = (const float*)d_in[14];
  float* out = (float*)d_out;

  char* w = (char*)d_ws;
  size_t off = 0;
  auto alloc = [&](size_t bytes) -> void* {
    void* p = w + off;
    off = (off + bytes + 255) & ~(size_t)255;
    return p;
  };
  unsigned short* xhb   = (unsigned short*)alloc((size_t)N_NODES * 256 * 2); // bf16 conv outputs
  float*          hbuf  = (float*)alloc((size_t)N_NODES * 256 * 4);          // conv1 aggregate (fp32)
  unsigned short* B1hi  = (unsigned short*)alloc(256 * 256 * 2);
  unsigned short* B1lo  = (unsigned short*)alloc(256 * 256 * 2);
  unsigned short* B2hi  = (unsigned short*)alloc(128 * 256 * 2);
  unsigned short* B2lo  = (unsigned short*)alloc(128 * 256 * 2);
  int*      rowptr   = (int*)alloc((N_NODES + 1) * 4);
  int*      cnt      = (int*)alloc(N_NODES * 4);
  int*      rank     = (int*)alloc((size_t)N_EDGES * 4);
  int*      bsum     = (int*)alloc(256 * 4);
  uint2*    ecsr     = (uint2*)alloc((size_t)EP * 8);
  float*    asrc     = (float*)alloc(N_NODES * 2 * 4);
  float*    adst     = (float*)alloc(N_NODES * 2 * 4);
  float*    Ae       = (float*)alloc(16 * 4);

  auto cdiv = [](int a, int b) { return (a + b - 1) / b; };

  // graph prep: one atomic pass (rank) -> scan -> computed scatter -> fused misc prep
  fill_u32<<<cdiv(N_NODES, 256), 256, 0, stream>>>((unsigned*)cnt, 0u, N_NODES);
  rank_pass<<<cdiv(N_EDGES, 256), 256, 0, stream>>>(ei, cnt, rank);
  block_sums<<<SCAN_BLOCKS, 256, 0, stream>>>(cnt, bsum);
  emit_rowptr<<<SCAN_BLOCKS, 256, 0, stream>>>(cnt, bsum, rowptr);
  scatter_pass<<<cdiv(N_EDGES, 256), 256, 0, stream>>>(ei, ea, rowptr, rank, ecsr);
  prep_misc<<<MISC_LATTR + MISC_BT + 6, 256, 0, stream>>>(rowptr, ecsr, W1, W2,
                                                          B1hi, B1lo, B2hi, B2lo,
                                                          ae1, ae2, We1, We2, Ae);

  // ---- conv1 (H=2, C=128) ----
  gemm_split<2><<<dim3(2, cdiv(N_NODES, 64)), 256, 0, stream>>>(x, B1hi, B1lo, xhb, N_NODES, 256,
                                                                as1, ad1, asrc, adst);
  aggregate_fused<2, 1><<<cdiv(N_NODES, 4), 256, 0, stream>>>(xhb, asrc, adst, ecsr, rowptr,
                                                              Ae, 0, b1, hbuf);

  // ---- conv2 (H=1, C=128) ----
  gemm_split<1><<<dim3(1, cdiv(N_NODES, 64)), 256, 0, stream>>>(hbuf, B2hi, B2lo, xhb, N_NODES, 128,
                                                                as2, ad2, asrc, adst);
  aggregate_fused<1, 0><<<cdiv(N_NODES, 4), 256, 0, stream>>>(xhb, asrc, adst, ecsr, rowptr,
                                                              Ae, 4, b2, out);
}

// Round 14
// 237.154 us; speedup vs baseline: 1.0456x; 1.0456x over previous
//
#include <hip/hip_runtime.h>
#include <math.h>

#define N_NODES 50000
#define N_EDGES 800000
#define EP (N_EDGES + N_NODES)   // edges incl. self loops
#define NEG_SLOPE 0.2f
#define SCAN_BLOCKS ((N_NODES + 255) / 256)   // 196

typedef __attribute__((ext_vector_type(8))) short bf16x8;
typedef __attribute__((ext_vector_type(4))) float f32x4;

// ---------- helpers ----------
__device__ __forceinline__ unsigned short f2bf(float f) {
  unsigned u = __float_as_uint(f);
  unsigned r = (u + 0x7FFFu + ((u >> 16) & 1u)) >> 16;
  return (unsigned short)r;
}
__device__ __forceinline__ float bf2f(unsigned short b) {
  return __uint_as_float(((unsigned)b) << 16);
}

__global__ void fill_u32(unsigned* p, unsigned v, int n) {
  int i = blockIdx.x * blockDim.x + threadIdx.x;
  if (i < n) p[i] = v;
}

// ---------- pass 1: per-dst rank; 8 shadow counter arrays (copy = blockIdx&7) ------
// On the default round-robin block->XCD mapping each copy stays XCD-L2-local.
// Correctness does not depend on the mapping: copy is reconstructible from e.
__global__ void rank_pass8(const int* __restrict__ ei, int* __restrict__ cnt8,
                           int* __restrict__ rank) {
  int e = blockIdx.x * blockDim.x + threadIdx.x;
  if (e >= N_EDGES) return;
  int c = blockIdx.x & 7;
  rank[e] = atomicAdd(&cnt8[c * N_NODES + ei[N_EDGES + e]], 1);
}

// ---------- combine: per-node totals + per-copy exclusive offsets (in place) -------
__global__ void combine8(int* __restrict__ cnt8, int* __restrict__ cnt) {
  int n = blockIdx.x * blockDim.x + threadIdx.x;
  if (n >= N_NODES) return;
  int running = 0;
  #pragma unroll
  for (int c = 0; c < 8; ++c) {
    int v = cnt8[c * N_NODES + n];
    cnt8[c * N_NODES + n] = running;   // exclusive prefix for this copy
    running += v;
  }
  cnt[n] = running;
}

// ---------- block sums of (cnt+1) ----------
__global__ void block_sums(const int* __restrict__ cnt, int* __restrict__ bsum) {
  __shared__ int ws[4];
  int b = blockIdx.x;
  int i = b * 256 + threadIdx.x;
  int v = (i < N_NODES) ? (cnt[i] + 1) : 0;   // +1 = self loop
  #pragma unroll
  for (int off = 32; off > 0; off >>= 1) v += __shfl_down(v, off);
  if ((threadIdx.x & 63) == 0) ws[threadIdx.x >> 6] = v;
  __syncthreads();
  if (threadIdx.x == 0) bsum[b] = ws[0] + ws[1] + ws[2] + ws[3];
}

// ---------- rowptr emit with fused top-level scan (each block scans bsum) --------
__global__ void emit_rowptr(const int* __restrict__ cnt, const int* __restrict__ bsum,
                            int* __restrict__ rowptr) {
  __shared__ int buf[2][256];
  int b = blockIdx.x, t = threadIdx.x;
  int vb = (t < SCAN_BLOCKS) ? bsum[t] : 0;
  buf[0][t] = vb;
  __syncthreads();
  int cur = 0;
  for (int off = 1; off < 256; off <<= 1) {
    int x = buf[cur][t];
    if (t >= off) x += buf[cur][t - off];
    buf[cur ^ 1][t] = x;
    cur ^= 1;
    __syncthreads();
  }
  int base = buf[cur][b] - ((b < SCAN_BLOCKS) ? bsum[b] : 0);  // exclusive prefix
  __syncthreads();
  int i = b * 256 + t;
  int v = (i < N_NODES) ? (cnt[i] + 1) : 0;
  buf[cur][t] = v;
  __syncthreads();
  int c2 = cur;
  for (int off = 1; off < 256; off <<= 1) {
    int x = buf[c2][t];
    if (t >= off) x += buf[c2][t - off];
    buf[c2 ^ 1][t] = x;
    c2 ^= 1;
    __syncthreads();
  }
  int incl = buf[c2][t];
  if (i < N_NODES) {
    rowptr[i] = base + incl - v;
    if (i == N_NODES - 1) rowptr[N_NODES] = base + incl;
  }
}

// ---------- pass 2: computed scatter (NO atomics); self-loop slot = end-1 ----------
__global__ void scatter_pass(const int* __restrict__ ei, const float* __restrict__ ea,
                             const int* __restrict__ rowptr, const int* __restrict__ rank,
                             const int* __restrict__ cnt8, uint2* __restrict__ ecsr) {
  int e = blockIdx.x * blockDim.x + threadIdx.x;
  if (e >= N_EDGES) return;
  int d = ei[N_EDGES + e];
  int c = blockIdx.x & 7;            // same copy id as rank_pass8 (same grid shape)
  int pos = rowptr[d] + cnt8[c * N_NODES + d] + rank[e];
  uint2 v;
  v.x = (unsigned)ei[e];
  v.y = (unsigned)f2bf(ea[2 * e]) | ((unsigned)f2bf(ea[2 * e + 1]) << 16);
  ecsr[pos] = v;
}

// ---------- fused misc prep: lattr_fin + bt_split + prep_ae (role by blockIdx) ----
#define MISC_LATTR 196
#define MISC_BT    384
__global__ void prep_misc(const int* __restrict__ rowptr, uint2* __restrict__ ecsr,
                          const float* __restrict__ W1, const float* __restrict__ W2,
                          unsigned short* __restrict__ b1h, unsigned short* __restrict__ b1l,
                          unsigned short* __restrict__ b2h, unsigned short* __restrict__ b2l,
                          const float* __restrict__ ae1, const float* __restrict__ ae2,
                          const float* __restrict__ We1, const float* __restrict__ We2,
                          float* __restrict__ Ae) {
  int b = blockIdx.x;
  int t = threadIdx.x;
  if (b < MISC_LATTR) {
    // self-loop attr = mean of incoming ea; record at segment end-1
    int n = b * 256 + t;
    if (n >= N_NODES) return;
    int beg = rowptr[n], end = rowptr[n + 1];
    float s0 = 0.f, s1 = 0.f;
    for (int j = beg; j < end - 1; ++j) {
      unsigned p = ecsr[j].y;
      s0 += __uint_as_float(p << 16);
      s1 += __uint_as_float(p & 0xFFFF0000u);
    }
    float c = fmaxf((float)(end - 1 - beg), 1.0f);
    uint2 m;
    m.x = (unsigned)n;
    m.y = (unsigned)f2bf(s0 / c) | ((unsigned)f2bf(s1 / c) << 16);
    ecsr[end - 1] = m;
  } else if (b < MISC_LATTR + MISC_BT) {
    // W -> W^T hi/lo split
    int nb = b - MISC_LATTR;
    float v; unsigned short* ph; unsigned short* pl; int idx;
    if (nb < 256) { v = W1[t * 256 + nb];         ph = b1h; pl = b1l; idx = nb * 256 + t; }
    else          { v = W2[t * 128 + (nb - 256)]; ph = b2h; pl = b2l; idx = (nb - 256) * 256 + t; }
    unsigned short h = f2bf(v);
    ph[idx] = h;
    pl[idx] = f2bf(v - bf2f(h));
  } else {
    // Ae[d][h] = sum_c We[d, h*128+c] * att_e[h,c]
    if (t >= 64) return;
    int bb = b - (MISC_LATTR + MISC_BT);   // 0..5
    float s = 0.f;
    if (bb < 4) {
      int d = bb >> 1, h = bb & 1;
      for (int c = t; c < 128; c += 64)
        s += We1[d * 256 + h * 128 + c] * ae1[h * 128 + c];
    } else {
      int d = bb - 4;
      for (int c = t; c < 128; c += 64)
        s += We2[d * 128 + c] * ae2[c];
    }
    for (int off = 32; off > 0; off >>= 1) s += __shfl_down(s, off);
    if (t == 0) Ae[bb] = s;  // [d0h0, d0h1, d1h0, d1h1, d0(conv2), d1(conv2)]
  }
}

// ---------- split-bf16 MFMA GEMM (fp32-accurate) with fused attention epilogue ----
template <int H>
__global__ __launch_bounds__(256) void gemm_split(
    const float* __restrict__ A,
    const unsigned short* __restrict__ Bth, const unsigned short* __restrict__ Btl,
    unsigned short* __restrict__ C, int M, int N,
    const float* __restrict__ att_src, const float* __restrict__ att_dst,
    float* __restrict__ asrc, float* __restrict__ adst) {
  __shared__ __attribute__((aligned(16))) unsigned short As[2][64][40];
  __shared__ __attribute__((aligned(16))) unsigned short Bs[2][128][40];
  __shared__ float redS[2][64], redD[2][64];   // [wc][row_local]
  int bm = blockIdx.y * 64, bn = blockIdx.x * 128;
  int tid = threadIdx.x;
  int l = tid & 63;
  int wid = tid >> 6;
  int wr = wid >> 1, wc = wid & 1;
  int rr = l & 15, kc = l >> 4;

  f32x4 acc[2][4];
  #pragma unroll
  for (int i = 0; i < 2; ++i)
    #pragma unroll
    for (int j = 0; j < 4; ++j)
      acc[i][j] = (f32x4){0.f, 0.f, 0.f, 0.f};

  int ar = tid >> 2, ac = tid & 3;
  int gm = bm + ar;

  for (int kt = 0; kt < 8; ++kt) {
    int k0 = kt * 32;
    float4 f0 = {0.f, 0.f, 0.f, 0.f}, f1 = f0;
    if (gm < M) {
      f0 = *(const float4*)(A + (size_t)gm * 256 + k0 + ac * 8);
      f1 = *(const float4*)(A + (size_t)gm * 256 + k0 + ac * 8 + 4);
    }
    float f[8] = {f0.x, f0.y, f0.z, f0.w, f1.x, f1.y, f1.z, f1.w};
    unsigned hw[4], lw[4];
    #pragma unroll
    for (int q = 0; q < 4; ++q) {
      unsigned short ha = f2bf(f[2 * q]),  hb = f2bf(f[2 * q + 1]);
      unsigned short la = f2bf(f[2 * q] - bf2f(ha)), lb = f2bf(f[2 * q + 1] - bf2f(hb));
      hw[q] = (unsigned)ha | ((unsigned)hb << 16);
      lw[q] = (unsigned)la | ((unsigned)lb << 16);
    }
    *(uint4*)&As[0][ar][ac * 8] = make_uint4(hw[0], hw[1], hw[2], hw[3]);
    *(uint4*)&As[1][ar][ac * 8] = make_uint4(lw[0], lw[1], lw[2], lw[3]);
    #pragma unroll
    for (int p = 0; p < 2; ++p) {
      int id = tid + p * 256;
      int nn = id >> 2, cc = id & 3;
      *(uint4*)&Bs[0][nn][cc * 8] = *(const uint4*)(Bth + (size_t)(bn + nn) * 256 + k0 + cc * 8);
      *(uint4*)&Bs[1][nn][cc * 8] = *(const uint4*)(Btl + (size_t)(bn + nn) * 256 + k0 + cc * 8);
    }
    __syncthreads();
    bf16x8 ah[2], alo[2], bh[4], bl[4];
    #pragma unroll
    for (int i = 0; i < 2; ++i) {
      ah[i]  = *(const bf16x8*)&As[0][wr * 32 + i * 16 + rr][kc * 8];
      alo[i] = *(const bf16x8*)&As[1][wr * 32 + i * 16 + rr][kc * 8];
    }
    #pragma unroll
    for (int j = 0; j < 4; ++j) {
      bh[j] = *(const bf16x8*)&Bs[0][wc * 64 + j * 16 + rr][kc * 8];
      bl[j] = *(const bf16x8*)&Bs[1][wc * 64 + j * 16 + rr][kc * 8];
    }
    #pragma unroll
    for (int i = 0; i < 2; ++i)
      #pragma unroll
      for (int j = 0; j < 4; ++j) {
        acc[i][j] = __builtin_amdgcn_mfma_f32_16x16x32_bf16(ah[i],  bh[j], acc[i][j], 0, 0, 0);
        acc[i][j] = __builtin_amdgcn_mfma_f32_16x16x32_bf16(ah[i],  bl[j], acc[i][j], 0, 0, 0);
        acc[i][j] = __builtin_amdgcn_mfma_f32_16x16x32_bf16(alo[i], bh[j], acc[i][j], 0, 0, 0);
      }
    __syncthreads();
  }

  // C store (bf16)
  #pragma unroll
  for (int i = 0; i < 2; ++i)
    #pragma unroll
    for (int reg = 0; reg < 4; ++reg) {
      int row = bm + wr * 32 + i * 16 + kc * 4 + reg;
      if (row < M) {
        #pragma unroll
        for (int j = 0; j < 4; ++j) {
          int col = bn + wc * 64 + j * 16 + rr;
          C[(size_t)row * N + col] = f2bf(acc[i][j][reg]);
        }
      }
    }

  // fused attention dot products: per-wave partials -> LDS -> direct store
  int head = (H == 2) ? (bn >> 7) : 0;
  float ats[4], atd[4];
  #pragma unroll
  for (int j = 0; j < 4; ++j) {
    int colh = wc * 64 + j * 16 + rr;
    ats[j] = att_src[head * 128 + colh];
    atd[j] = att_dst[head * 128 + colh];
  }
  #pragma unroll
  for (int i = 0; i < 2; ++i)
    #pragma unroll
    for (int reg = 0; reg < 4; ++reg) {
      float sp = acc[i][0][reg] * ats[0] + acc[i][1][reg] * ats[1] +
                 acc[i][2][reg] * ats[2] + acc[i][3][reg] * ats[3];
      float dp = acc[i][0][reg] * atd[0] + acc[i][1][reg] * atd[1] +
                 acc[i][2][reg] * atd[2] + acc[i][3][reg] * atd[3];
      #pragma unroll
      for (int off = 1; off < 16; off <<= 1) {
        sp += __shfl_xor(sp, off);
        dp += __shfl_xor(dp, off);
      }
      if (rr == 0) {
        int row_local = wr * 32 + i * 16 + kc * 4 + reg;
        redS[wc][row_local] = sp;
        redD[wc][row_local] = dp;
      }
    }
  __syncthreads();
  if (tid < 64) {
    int row = bm + tid;
    if (row < M) {
      asrc[row * H + head] = redS[0][tid] + redS[1][tid];
      adst[row * H + head] = redD[0][tid] + redD[1][tid];
    }
  }
}

// ---------- fused: logits + exp + denom + weighted aggregation (R11/R7 structure) --
// One wave per node; LDS staging of exp/src; COLS packed-bf16 columns per thread.
template <int H, int ACT>
__global__ __launch_bounds__(64)
void aggregate_fused(const unsigned short* __restrict__ xh, const float* __restrict__ asrc,
                     const float* __restrict__ adst, const uint2* __restrict__ ecsr,
                     const int* __restrict__ rowptr,
                     const float* __restrict__ Ae, int aeoff,
                     const float* __restrict__ bias, float* __restrict__ out) {
  constexpr int D = H * 128;
  constexpr int COLS = D / 64;       // 4 (conv1) or 2 (conv2)
  __shared__ float exl[256][H];
  __shared__ int sl[256];
  int n = blockIdx.x;
  int t = threadIdx.x;               // 0..63
  int beg = rowptr[n], end = rowptr[n + 1];
  int hA = t & (H - 1);              // phase-A head (fixed per thread)
  float adnA = adst[n * H + hA];
  float Ae0 = Ae[aeoff + hA], Ae1 = Ae[aeoff + H + hA];
  int hB = (H == 2) ? (t >> 5) : 0;  // phase-B head (cols COLS*t..COLS*t+COLS-1)
  float lsum = 0.f;
  float acc[4][COLS];
  #pragma unroll
  for (int q = 0; q < 4; ++q)
    #pragma unroll
    for (int c = 0; c < COLS; ++c) acc[q][c] = 0.f;

  for (int cbeg = beg; cbeg < end; cbeg += 256) {
    int cnt = min(256, end - cbeg);
    for (int idx = t; idx < cnt * H; idx += 64) {
      int j0 = (H == 2) ? (idx >> 1) : idx;
      uint2 ev = ecsr[cbeg + j0];
      int s = (int)ev.x;
      float ea0 = __uint_as_float(ev.y << 16);
      float ea1 = __uint_as_float(ev.y & 0xFFFF0000u);
      float lg = asrc[s * H + hA] + adnA + ea0 * Ae0 + ea1 * Ae1;
      lg = (lg > 0.f) ? lg : NEG_SLOPE * lg;
      float ex = __expf(lg);
      exl[j0][hA] = ex;
      if (hA == 0) sl[j0] = s;
      lsum += ex;
    }
    __syncthreads();
    int j = 0;
    for (; j + 8 <= cnt; j += 8) {
      #pragma unroll
      for (int q = 0; q < 8; ++q) {
        float e = exl[j + q][hB];
        int s = sl[j + q];
        if (COLS == 4) {
          uint2 u = *(const uint2*)(xh + (size_t)s * D + 4 * t);
          acc[q & 3][0] = fmaf(e, __uint_as_float(u.x << 16), acc[q & 3][0]);
          acc[q & 3][1] = fmaf(e, __uint_as_float(u.x & 0xFFFF0000u), acc[q & 3][1]);
          acc[q & 3][2] = fmaf(e, __uint_as_float(u.y << 16), acc[q & 3][2]);
          acc[q & 3][3] = fmaf(e, __uint_as_float(u.y & 0xFFFF0000u), acc[q & 3][3]);
        } else {
          unsigned u = *(const unsigned*)(xh + (size_t)s * D + 2 * t);
          acc[q & 3][0] = fmaf(e, __uint_as_float(u << 16), acc[q & 3][0]);
          acc[q & 3][1] = fmaf(e, __uint_as_float(u & 0xFFFF0000u), acc[q & 3][1]);
        }
      }
    }
    for (; j < cnt; ++j) {
      float e = exl[j][hB];
      int s = sl[j];
      if (COLS == 4) {
        uint2 u = *(const uint2*)(xh + (size_t)s * D + 4 * t);
        acc[0][0] = fmaf(e, __uint_as_float(u.x << 16), acc[0][0]);
        acc[0][1] = fmaf(e, __uint_as_float(u.x & 0xFFFF0000u), acc[0][1]);
        acc[0][2] = fmaf(e, __uint_as_float(u.y << 16), acc[0][2]);
        acc[0][3] = fmaf(e, __uint_as_float(u.y & 0xFFFF0000u), acc[0][3]);
      } else {
        unsigned u = *(const unsigned*)(xh + (size_t)s * D + 2 * t);
        acc[0][0] = fmaf(e, __uint_as_float(u << 16), acc[0][0]);
        acc[0][1] = fmaf(e, __uint_as_float(u & 0xFFFF0000u), acc[0][1]);
      }
    }
    __syncthreads();
  }

  // wave-only reduction of lsum per head-parity class
  #pragma unroll
  for (int off = H; off < 64; off <<= 1) lsum += __shfl_xor(lsum, off);
  float tot = (H == 2) ? __shfl(lsum, hB) : lsum;
  float inv = 1.0f / (tot + 1e-16f);

  float v[COLS];
  #pragma unroll
  for (int c = 0; c < COLS; ++c) {
    v[c] = fmaf(inv, (acc[0][c] + acc[1][c]) + (acc[2][c] + acc[3][c]),
                bias[COLS * t + c]);
    if (ACT) v[c] = (v[c] > 0.f) ? v[c] : expm1f(v[c]);
  }
  if (COLS == 4) {
    *(float4*)(out + (size_t)n * D + 4 * t) = make_float4(v[0], v[1], v[2], v[3]);
  } else {
    *(float2*)(out + (size_t)n * D + 2 * t) = make_float2(v[0], v[1]);
  }
}

// ---------- launch ----------
extern "C" void kernel_launch(void* const* d_in, const int* in_sizes, int n_in,
                              void* d_out, int out_size, void* d_ws, size_t ws_size,
                              hipStream_t stream) {
  const float* x    = (const float*)d_in[0];
  const int*   ei   = (const int*)d_in[1];
  const float* ea   = (const float*)d_in[2];
  const float* W1   = (const float*)d_in[3];
  const float* as1  = (const float*)d_in[4];
  const float* ad1  = (const float*)d_in[5];
  const float* We1  = (const float*)d_in[6];
  const float* ae1  = (const float*)d_in[7];
  const float* b1   = (const float*)d_in[8];
  const float* W2   = (const float*)d_in[9];
  const float* as2  = (const float*)d_in[10];
  const float* ad2  = (const float*)d_in[11];
  const float* We2  = (const float*)d_in[12];
  const float* ae2  = (const float*)d_in[13];
  const float* b2   = (const float*)d_in[14];
  float* out = (float*)d_out;

  char* w = (char*)d_ws;
  size_t off = 0;
  auto alloc = [&](size_t bytes) -> void* {
    void* p = w + off;
    off = (off + bytes + 255) & ~(size_t)255;
    return p;
  };
  unsigned short* xhb   = (unsigned short*)alloc((size_t)N_NODES * 256 * 2); // bf16 conv outputs
  float*          hbuf  = (float*)alloc((size_t)N_NODES * 256 * 4);          // conv1 aggregate (fp32)
  unsigned short* B1hi  = (unsigned short*)alloc(256 * 256 * 2);
  unsigned short* B1lo  = (unsigned short*)alloc(256 * 256 * 2);
  unsigned short* B2hi  = (unsigned short*)alloc(128 * 256 * 2);
  unsigned short* B2lo  = (unsigned short*)alloc(128 * 256 * 2);
  int*      rowptr   = (int*)alloc((N_NODES + 1) * 4);
  int*      cnt      = (int*)alloc(N_NODES * 4);
  int*      cnt8     = (int*)alloc((size_t)N_NODES * 8 * 4);
  int*      rank     = (int*)alloc((size_t)N_EDGES * 4);
  int*      bsum     = (int*)alloc(256 * 4);
  uint2*    ecsr     = (uint2*)alloc((size_t)EP * 8);
  float*    asrc     = (float*)alloc(N_NODES * 2 * 4);
  float*    adst     = (float*)alloc(N_NODES * 2 * 4);
  float*    Ae       = (float*)alloc(16 * 4);

  auto cdiv = [](int a, int b) { return (a + b - 1) / b; };

  // graph prep: shadow-counter rank pass -> combine -> scan -> computed scatter -> misc
  fill_u32<<<cdiv(N_NODES * 8, 256), 256, 0, stream>>>((unsigned*)cnt8, 0u, N_NODES * 8);
  rank_pass8<<<cdiv(N_EDGES, 256), 256, 0, stream>>>(ei, cnt8, rank);
  combine8<<<cdiv(N_NODES, 256), 256, 0, stream>>>(cnt8, cnt);
  block_sums<<<SCAN_BLOCKS, 256, 0, stream>>>(cnt, bsum);
  emit_rowptr<<<SCAN_BLOCKS, 256, 0, stream>>>(cnt, bsum, rowptr);
  scatter_pass<<<cdiv(N_EDGES, 256), 256, 0, stream>>>(ei, ea, rowptr, rank, cnt8, ecsr);
  prep_misc<<<MISC_LATTR + MISC_BT + 6, 256, 0, stream>>>(rowptr, ecsr, W1, W2,
                                                          B1hi, B1lo, B2hi, B2lo,
                                                          ae1, ae2, We1, We2, Ae);

  // ---- conv1 (H=2, C=128) ----
  gemm_split<2><<<dim3(2, cdiv(N_NODES, 64)), 256, 0, stream>>>(x, B1hi, B1lo, xhb, N_NODES, 256,
                                                                as1, ad1, asrc, adst);
  aggregate_fused<2, 1><<<N_NODES, 64, 0, stream>>>(xhb, asrc, adst, ecsr, rowptr,
                                                    Ae, 0, b1, hbuf);

  // ---- conv2 (H=1, C=128) ----
  gemm_split<1><<<dim3(1, cdiv(N_NODES, 64)), 256, 0, stream>>>(hbuf, B2hi, B2lo, xhb, N_NODES, 128,
                                                                as2, ad2, asrc, adst);
  aggregate_fused<1, 0><<<N_NODES, 64, 0, stream>>>(xhb, asrc, adst, ecsr, rowptr,
                                                    Ae, 4, b2, out);
}

// Round 15
// 214.744 us; speedup vs baseline: 1.1547x; 1.1044x over previous
//
#include <hip/hip_runtime.h>
#include <math.h>

#define N_NODES 50000
#define N_EDGES 800000
#define EP (N_EDGES + N_NODES)
#define NEG_SLOPE 0.2f
#define SCAN_BLOCKS ((N_NODES + 255) / 256)        // 196
#define GEMM1B (2 * ((N_NODES + 63) / 64))         // 1564
#define RANKB ((N_EDGES + 255) / 256)              // 3125
#define FILLB ((N_NODES * 8 + 255) / 256)          // 1563

typedef __attribute__((ext_vector_type(8))) short bf16x8;
typedef __attribute__((ext_vector_type(4))) float f32x4;

// ---------- helpers ----------
__device__ __forceinline__ unsigned short f2bf(float f) {
  unsigned u = __float_as_uint(f);
  unsigned r = (u + 0x7FFFu + ((u >> 16) & 1u)) >> 16;
  return (unsigned short)r;
}
__device__ __forceinline__ float bf2f(unsigned short b) {
  return __uint_as_float(((unsigned)b) << 16);
}

// ---------- fused input-only prep: zero cnt8 | W->W^T hi/lo split | Ae ----------
__global__ void prep_inputs(int* __restrict__ cnt8,
                            const float* __restrict__ W1, const float* __restrict__ W2,
                            unsigned short* __restrict__ b1h, unsigned short* __restrict__ b1l,
                            unsigned short* __restrict__ b2h, unsigned short* __restrict__ b2l,
                            const float* __restrict__ ae1, const float* __restrict__ ae2,
                            const float* __restrict__ We1, const float* __restrict__ We2,
                            float* __restrict__ Ae) {
  int b = blockIdx.x;
  int t = threadIdx.x;
  if (b < FILLB) {
    int i = b * 256 + t;
    if (i < N_NODES * 8) cnt8[i] = 0;
  } else if (b < FILLB + 384) {
    int nb = b - FILLB;
    float v; unsigned short* ph; unsigned short* pl; int idx;
    if (nb < 256) { v = W1[t * 256 + nb];         ph = b1h; pl = b1l; idx = nb * 256 + t; }
    else          { v = W2[t * 128 + (nb - 256)]; ph = b2h; pl = b2l; idx = (nb - 256) * 256 + t; }
    unsigned short h = f2bf(v);
    ph[idx] = h;
    pl[idx] = f2bf(v - bf2f(h));
  } else {
    if (t >= 64) return;
    int bb = b - (FILLB + 384);   // 0..5
    float s = 0.f;
    if (bb < 4) {
      int d = bb >> 1, h = bb & 1;
      for (int c = t; c < 128; c += 64)
        s += We1[d * 256 + h * 128 + c] * ae1[h * 128 + c];
    } else {
      int d = bb - 4;
      for (int c = t; c < 128; c += 64)
        s += We2[d * 128 + c] * ae2[c];
    }
    for (int off = 32; off > 0; off >>= 1) s += __shfl_down(s, off);
    if (t == 0) Ae[bb] = s;   // [d0h0, d0h1, d1h0, d1h1, d0(conv2), d1(conv2)]
  }
}

// ---------- fused conv1 GEMM (H=2) + rank pass (independent chains overlap) --------
__global__ __launch_bounds__(256) void gemm1_rank(
    const float* __restrict__ A,
    const unsigned short* __restrict__ Bth, const unsigned short* __restrict__ Btl,
    unsigned short* __restrict__ C,
    const float* __restrict__ att_src, const float* __restrict__ att_dst,
    float* __restrict__ asrc, float* __restrict__ adst,
    const int* __restrict__ ei, int* __restrict__ cnt8, int* __restrict__ rank) {
  __shared__ __attribute__((aligned(16))) unsigned short As[2][64][40];
  __shared__ __attribute__((aligned(16))) unsigned short Bs[2][128][40];
  __shared__ float redS[2][64], redD[2][64];
  int tid = threadIdx.x;

  if (blockIdx.x >= GEMM1B) {
    // ---- rank role: 1 atomic per edge into XCD-local shadow counters ----
    int bl = blockIdx.x - GEMM1B;
    int e = bl * 256 + tid;
    if (e < N_EDGES)
      rank[e] = atomicAdd(&cnt8[(bl & 7) * N_NODES + ei[N_EDGES + e]], 1);
    return;
  }

  // ---- GEMM role: C_bf16[M,256] = A_f32 @ B, split-bf16, attn epilogue ----
  const int M = N_NODES, N = 256;
  int bm = (blockIdx.x >> 1) * 64, bn = (blockIdx.x & 1) * 128;
  int l = tid & 63;
  int wid = tid >> 6;
  int wr = wid >> 1, wc = wid & 1;
  int rr = l & 15, kc = l >> 4;

  f32x4 acc[2][4];
  #pragma unroll
  for (int i = 0; i < 2; ++i)
    #pragma unroll
    for (int j = 0; j < 4; ++j)
      acc[i][j] = (f32x4){0.f, 0.f, 0.f, 0.f};

  int ar = tid >> 2, ac = tid & 3;
  int gm = bm + ar;

  for (int kt = 0; kt < 8; ++kt) {
    int k0 = kt * 32;
    float4 f0 = {0.f, 0.f, 0.f, 0.f}, f1 = f0;
    if (gm < M) {
      f0 = *(const float4*)(A + (size_t)gm * 256 + k0 + ac * 8);
      f1 = *(const float4*)(A + (size_t)gm * 256 + k0 + ac * 8 + 4);
    }
    float f[8] = {f0.x, f0.y, f0.z, f0.w, f1.x, f1.y, f1.z, f1.w};
    unsigned hw[4], lw[4];
    #pragma unroll
    for (int q = 0; q < 4; ++q) {
      unsigned short ha = f2bf(f[2 * q]),  hb = f2bf(f[2 * q + 1]);
      unsigned short la = f2bf(f[2 * q] - bf2f(ha)), lb = f2bf(f[2 * q + 1] - bf2f(hb));
      hw[q] = (unsigned)ha | ((unsigned)hb << 16);
      lw[q] = (unsigned)la | ((unsigned)lb << 16);
    }
    *(uint4*)&As[0][ar][ac * 8] = make_uint4(hw[0], hw[1], hw[2], hw[3]);
    *(uint4*)&As[1][ar][ac * 8] = make_uint4(lw[0], lw[1], lw[2], lw[3]);
    #pragma unroll
    for (int p = 0; p < 2; ++p) {
      int id = tid + p * 256;
      int nn = id >> 2, cc = id & 3;
      *(uint4*)&Bs[0][nn][cc * 8] = *(const uint4*)(Bth + (size_t)(bn + nn) * 256 + k0 + cc * 8);
      *(uint4*)&Bs[1][nn][cc * 8] = *(const uint4*)(Btl + (size_t)(bn + nn) * 256 + k0 + cc * 8);
    }
    __syncthreads();
    bf16x8 ah[2], alo[2], bh[4], bl[4];
    #pragma unroll
    for (int i = 0; i < 2; ++i) {
      ah[i]  = *(const bf16x8*)&As[0][wr * 32 + i * 16 + rr][kc * 8];
      alo[i] = *(const bf16x8*)&As[1][wr * 32 + i * 16 + rr][kc * 8];
    }
    #pragma unroll
    for (int j = 0; j < 4; ++j) {
      bh[j] = *(const bf16x8*)&Bs[0][wc * 64 + j * 16 + rr][kc * 8];
      bl[j] = *(const bf16x8*)&Bs[1][wc * 64 + j * 16 + rr][kc * 8];
    }
    #pragma unroll
    for (int i = 0; i < 2; ++i)
      #pragma unroll
      for (int j = 0; j < 4; ++j) {
        acc[i][j] = __builtin_amdgcn_mfma_f32_16x16x32_bf16(ah[i],  bh[j], acc[i][j], 0, 0, 0);
        acc[i][j] = __builtin_amdgcn_mfma_f32_16x16x32_bf16(ah[i],  bl[j], acc[i][j], 0, 0, 0);
        acc[i][j] = __builtin_amdgcn_mfma_f32_16x16x32_bf16(alo[i], bh[j], acc[i][j], 0, 0, 0);
      }
    __syncthreads();
  }

  #pragma unroll
  for (int i = 0; i < 2; ++i)
    #pragma unroll
    for (int reg = 0; reg < 4; ++reg) {
      int row = bm + wr * 32 + i * 16 + kc * 4 + reg;
      if (row < M) {
        #pragma unroll
        for (int j = 0; j < 4; ++j) {
          int col = bn + wc * 64 + j * 16 + rr;
          C[(size_t)row * N + col] = f2bf(acc[i][j][reg]);
        }
      }
    }

  int head = bn >> 7;
  float ats[4], atd[4];
  #pragma unroll
  for (int j = 0; j < 4; ++j) {
    int colh = wc * 64 + j * 16 + rr;
    ats[j] = att_src[head * 128 + colh];
    atd[j] = att_dst[head * 128 + colh];
  }
  #pragma unroll
  for (int i = 0; i < 2; ++i)
    #pragma unroll
    for (int reg = 0; reg < 4; ++reg) {
      float sp = acc[i][0][reg] * ats[0] + acc[i][1][reg] * ats[1] +
                 acc[i][2][reg] * ats[2] + acc[i][3][reg] * ats[3];
      float dp = acc[i][0][reg] * atd[0] + acc[i][1][reg] * atd[1] +
                 acc[i][2][reg] * atd[2] + acc[i][3][reg] * atd[3];
      #pragma unroll
      for (int off = 1; off < 16; off <<= 1) {
        sp += __shfl_xor(sp, off);
        dp += __shfl_xor(dp, off);
      }
      if (rr == 0) {
        int row_local = wr * 32 + i * 16 + kc * 4 + reg;
        redS[wc][row_local] = sp;
        redD[wc][row_local] = dp;
      }
    }
  __syncthreads();
  if (tid < 64) {
    int row = bm + tid;
    if (row < M) {
      asrc[row * 2 + head] = redS[0][tid] + redS[1][tid];
      adst[row * 2 + head] = redD[0][tid] + redD[1][tid];
    }
  }
}

// ---------- combine shadow counters -> per-copy prefixes + cnt + block sums -------
__global__ void combine_bsum(int* __restrict__ cnt8, int* __restrict__ cnt,
                             int* __restrict__ bsum) {
  __shared__ int ws[4];
  int b = blockIdx.x, t = threadIdx.x;
  int n = b * 256 + t;
  int running = 0;
  if (n < N_NODES) {
    #pragma unroll
    for (int c = 0; c < 8; ++c) {
      int v = cnt8[c * N_NODES + n];
      cnt8[c * N_NODES + n] = running;
      running += v;
    }
    cnt[n] = running;
  }
  int v = (n < N_NODES) ? (running + 1) : 0;   // +1 = self loop
  #pragma unroll
  for (int off = 32; off > 0; off >>= 1) v += __shfl_down(v, off);
  if ((t & 63) == 0) ws[t >> 6] = v;
  __syncthreads();
  if (t == 0) bsum[b] = ws[0] + ws[1] + ws[2] + ws[3];
}

// ---------- rowptr emit with fused top-level scan ----------
__global__ void emit_rowptr(const int* __restrict__ cnt, const int* __restrict__ bsum,
                            int* __restrict__ rowptr) {
  __shared__ int buf[2][256];
  int b = blockIdx.x, t = threadIdx.x;
  int vb = (t < SCAN_BLOCKS) ? bsum[t] : 0;
  buf[0][t] = vb;
  __syncthreads();
  int cur = 0;
  for (int off = 1; off < 256; off <<= 1) {
    int x = buf[cur][t];
    if (t >= off) x += buf[cur][t - off];
    buf[cur ^ 1][t] = x;
    cur ^= 1;
    __syncthreads();
  }
  int base = buf[cur][b] - ((b < SCAN_BLOCKS) ? bsum[b] : 0);
  __syncthreads();
  int i = b * 256 + t;
  int v = (i < N_NODES) ? (cnt[i] + 1) : 0;
  buf[cur][t] = v;
  __syncthreads();
  int c2 = cur;
  for (int off = 1; off < 256; off <<= 1) {
    int x = buf[c2][t];
    if (t >= off) x += buf[c2][t - off];
    buf[c2 ^ 1][t] = x;
    c2 ^= 1;
    __syncthreads();
  }
  int incl = buf[c2][t];
  if (i < N_NODES) {
    rowptr[i] = base + incl - v;
    if (i == N_NODES - 1) rowptr[N_NODES] = base + incl;
  }
}

// ---------- computed scatter (NO atomics); slot end-1 left for implicit self-loop --
__global__ void scatter_pass(const int* __restrict__ ei, const float* __restrict__ ea,
                             const int* __restrict__ rowptr, const int* __restrict__ rank,
                             const int* __restrict__ cnt8, uint2* __restrict__ ecsr) {
  int e = blockIdx.x * blockDim.x + threadIdx.x;
  if (e >= N_EDGES) return;
  int d = ei[N_EDGES + e];
  int c = blockIdx.x & 7;            // same copy id as rank role (same local block map)
  int pos = rowptr[d] + cnt8[c * N_NODES + d] + rank[e];
  uint2 v;
  v.x = (unsigned)ei[e];
  v.y = (unsigned)f2bf(ea[2 * e]) | ((unsigned)f2bf(ea[2 * e + 1]) << 16);
  ecsr[pos] = v;
}

// ---------- conv2 GEMM (H=1), standalone ----------
__global__ __launch_bounds__(256) void gemm_split1(
    const float* __restrict__ A,
    const unsigned short* __restrict__ Bth, const unsigned short* __restrict__ Btl,
    unsigned short* __restrict__ C, int M, int N,
    const float* __restrict__ att_src, const float* __restrict__ att_dst,
    float* __restrict__ asrc, float* __restrict__ adst) {
  __shared__ __attribute__((aligned(16))) unsigned short As[2][64][40];
  __shared__ __attribute__((aligned(16))) unsigned short Bs[2][128][40];
  __shared__ float redS[2][64], redD[2][64];
  int bm = blockIdx.y * 64, bn = blockIdx.x * 128;
  int tid = threadIdx.x;
  int l = tid & 63;
  int wid = tid >> 6;
  int wr = wid >> 1, wc = wid & 1;
  int rr = l & 15, kc = l >> 4;

  f32x4 acc[2][4];
  #pragma unroll
  for (int i = 0; i < 2; ++i)
    #pragma unroll
    for (int j = 0; j < 4; ++j)
      acc[i][j] = (f32x4){0.f, 0.f, 0.f, 0.f};

  int ar = tid >> 2, ac = tid & 3;
  int gm = bm + ar;

  for (int kt = 0; kt < 8; ++kt) {
    int k0 = kt * 32;
    float4 f0 = {0.f, 0.f, 0.f, 0.f}, f1 = f0;
    if (gm < M) {
      f0 = *(const float4*)(A + (size_t)gm * 256 + k0 + ac * 8);
      f1 = *(const float4*)(A + (size_t)gm * 256 + k0 + ac * 8 + 4);
    }
    float f[8] = {f0.x, f0.y, f0.z, f0.w, f1.x, f1.y, f1.z, f1.w};
    unsigned hw[4], lw[4];
    #pragma unroll
    for (int q = 0; q < 4; ++q) {
      unsigned short ha = f2bf(f[2 * q]),  hb = f2bf(f[2 * q + 1]);
      unsigned short la = f2bf(f[2 * q] - bf2f(ha)), lb = f2bf(f[2 * q + 1] - bf2f(hb));
      hw[q] = (unsigned)ha | ((unsigned)hb << 16);
      lw[q] = (unsigned)la | ((unsigned)lb << 16);
    }
    *(uint4*)&As[0][ar][ac * 8] = make_uint4(hw[0], hw[1], hw[2], hw[3]);
    *(uint4*)&As[1][ar][ac * 8] = make_uint4(lw[0], lw[1], lw[2], lw[3]);
    #pragma unroll
    for (int p = 0; p < 2; ++p) {
      int id = tid + p * 256;
      int nn = id >> 2, cc = id & 3;
      *(uint4*)&Bs[0][nn][cc * 8] = *(const uint4*)(Bth + (size_t)(bn + nn) * 256 + k0 + cc * 8);
      *(uint4*)&Bs[1][nn][cc * 8] = *(const uint4*)(Btl + (size_t)(bn + nn) * 256 + k0 + cc * 8);
    }
    __syncthreads();
    bf16x8 ah[2], alo[2], bh[4], bl[4];
    #pragma unroll
    for (int i = 0; i < 2; ++i) {
      ah[i]  = *(const bf16x8*)&As[0][wr * 32 + i * 16 + rr][kc * 8];
      alo[i] = *(const bf16x8*)&As[1][wr * 32 + i * 16 + rr][kc * 8];
    }
    #pragma unroll
    for (int j = 0; j < 4; ++j) {
      bh[j] = *(const bf16x8*)&Bs[0][wc * 64 + j * 16 + rr][kc * 8];
      bl[j] = *(const bf16x8*)&Bs[1][wc * 64 + j * 16 + rr][kc * 8];
    }
    #pragma unroll
    for (int i = 0; i < 2; ++i)
      #pragma unroll
      for (int j = 0; j < 4; ++j) {
        acc[i][j] = __builtin_amdgcn_mfma_f32_16x16x32_bf16(ah[i],  bh[j], acc[i][j], 0, 0, 0);
        acc[i][j] = __builtin_amdgcn_mfma_f32_16x16x32_bf16(ah[i],  bl[j], acc[i][j], 0, 0, 0);
        acc[i][j] = __builtin_amdgcn_mfma_f32_16x16x32_bf16(alo[i], bh[j], acc[i][j], 0, 0, 0);
      }
    __syncthreads();
  }

  #pragma unroll
  for (int i = 0; i < 2; ++i)
    #pragma unroll
    for (int reg = 0; reg < 4; ++reg) {
      int row = bm + wr * 32 + i * 16 + kc * 4 + reg;
      if (row < M) {
        #pragma unroll
        for (int j = 0; j < 4; ++j) {
          int col = bn + wc * 64 + j * 16 + rr;
          C[(size_t)row * N + col] = f2bf(acc[i][j][reg]);
        }
      }
    }

  float ats[4], atd[4];
  #pragma unroll
  for (int j = 0; j < 4; ++j) {
    int colh = wc * 64 + j * 16 + rr;
    ats[j] = att_src[colh];
    atd[j] = att_dst[colh];
  }
  #pragma unroll
  for (int i = 0; i < 2; ++i)
    #pragma unroll
    for (int reg = 0; reg < 4; ++reg) {
      float sp = acc[i][0][reg] * ats[0] + acc[i][1][reg] * ats[1] +
                 acc[i][2][reg] * ats[2] + acc[i][3][reg] * ats[3];
      float dp = acc[i][0][reg] * atd[0] + acc[i][1][reg] * atd[1] +
                 acc[i][2][reg] * atd[2] + acc[i][3][reg] * atd[3];
      #pragma unroll
      for (int off = 1; off < 16; off <<= 1) {
        sp += __shfl_xor(sp, off);
        dp += __shfl_xor(dp, off);
      }
      if (rr == 0) {
        int row_local = wr * 32 + i * 16 + kc * 4 + reg;
        redS[wc][row_local] = sp;
        redD[wc][row_local] = dp;
      }
    }
  __syncthreads();
  if (tid < 64) {
    int row = bm + tid;
    if (row < M) {
      asrc[row] = redS[0][tid] + redS[1][tid];
      adst[row] = redD[0][tid] + redD[1][tid];
    }
  }
}

// ---------- fused aggregation with IMPLICIT SELF-LOOP (no lattr pass) -------------
// One wave per node. Real edges in [beg, end-1); slot end-1 is virtual: the wave
// accumulates sum(ea), computes the mean in-register, adds the self-loop exp and
// its own-row message after the main loop. Math-identical to add_self_loops(mean).
template <int H, int ACT>
__global__ __launch_bounds__(64)
void aggregate_fused(const unsigned short* __restrict__ xh, const float* __restrict__ asrc,
                     const float* __restrict__ adst, const uint2* __restrict__ ecsr,
                     const int* __restrict__ rowptr,
                     const float* __restrict__ Ae, int aeoff,
                     const float* __restrict__ bias, float* __restrict__ out) {
  constexpr int D = H * 128;
  constexpr int COLS = D / 64;       // 4 (conv1) or 2 (conv2)
  __shared__ float exl[256][H];
  __shared__ int sl[256];
  int n = blockIdx.x;
  int t = threadIdx.x;               // 0..63
  int beg = rowptr[n], endE = rowptr[n + 1] - 1;   // real edges only
  int hA = t & (H - 1);
  float adnA = adst[n * H + hA];
  float Ae0 = Ae[aeoff + hA], Ae1 = Ae[aeoff + H + hA];
  int hB = (H == 2) ? (t >> 5) : 0;
  float lsum = 0.f;
  float sea0 = 0.f, sea1 = 0.f;      // sum of edge attrs (hA==0 lanes only)
  float acc[4][COLS];
  #pragma unroll
  for (int q = 0; q < 4; ++q)
    #pragma unroll
    for (int c = 0; c < COLS; ++c) acc[q][c] = 0.f;

  for (int cbeg = beg; cbeg < endE; cbeg += 256) {
    int cnt = min(256, endE - cbeg);
    for (int idx = t; idx < cnt * H; idx += 64) {
      int j0 = (H == 2) ? (idx >> 1) : idx;
      uint2 ev = ecsr[cbeg + j0];
      int s = (int)ev.x;
      float ea0 = __uint_as_float(ev.y << 16);
      float ea1 = __uint_as_float(ev.y & 0xFFFF0000u);
      float lg = asrc[s * H + hA] + adnA + ea0 * Ae0 + ea1 * Ae1;
      lg = (lg > 0.f) ? lg : NEG_SLOPE * lg;
      float ex = __expf(lg);
      exl[j0][hA] = ex;
      if (hA == 0) { sl[j0] = s; sea0 += ea0; sea1 += ea1; }
      lsum += ex;
    }
    __syncthreads();
    int j = 0;
    for (; j + 8 <= cnt; j += 8) {
      #pragma unroll
      for (int q = 0; q < 8; ++q) {
        float e = exl[j + q][hB];
        int s = sl[j + q];
        if (COLS == 4) {
          uint2 u = *(const uint2*)(xh + (size_t)s * D + 4 * t);
          acc[q & 3][0] = fmaf(e, __uint_as_float(u.x << 16), acc[q & 3][0]);
          acc[q & 3][1] = fmaf(e, __uint_as_float(u.x & 0xFFFF0000u), acc[q & 3][1]);
          acc[q & 3][2] = fmaf(e, __uint_as_float(u.y << 16), acc[q & 3][2]);
          acc[q & 3][3] = fmaf(e, __uint_as_float(u.y & 0xFFFF0000u), acc[q & 3][3]);
        } else {
          unsigned u = *(const unsigned*)(xh + (size_t)s * D + 2 * t);
          acc[q & 3][0] = fmaf(e, __uint_as_float(u << 16), acc[q & 3][0]);
          acc[q & 3][1] = fmaf(e, __uint_as_float(u & 0xFFFF0000u), acc[q & 3][1]);
        }
      }
    }
    for (; j < cnt; ++j) {
      float e = exl[j][hB];
      int s = sl[j];
      if (COLS == 4) {
        uint2 u = *(const uint2*)(xh + (size_t)s * D + 4 * t);
        acc[0][0] = fmaf(e, __uint_as_float(u.x << 16), acc[0][0]);
        acc[0][1] = fmaf(e, __uint_as_float(u.x & 0xFFFF0000u), acc[0][1]);
        acc[0][2] = fmaf(e, __uint_as_float(u.y << 16), acc[0][2]);
        acc[0][3] = fmaf(e, __uint_as_float(u.y & 0xFFFF0000u), acc[0][3]);
      } else {
        unsigned u = *(const unsigned*)(xh + (size_t)s * D + 2 * t);
        acc[0][0] = fmaf(e, __uint_as_float(u << 16), acc[0][0]);
        acc[0][1] = fmaf(e, __uint_as_float(u & 0xFFFF0000u), acc[0][1]);
      }
    }
    __syncthreads();
  }

  // self-loop: mean edge attr over real in-edges (0 if none)
  #pragma unroll
  for (int off = 1; off < 64; off <<= 1) {
    sea0 += __shfl_xor(sea0, off);
    sea1 += __shfl_xor(sea1, off);
  }
  float cdeg = fmaxf((float)(endE - beg), 1.0f);
  float m0 = sea0 / cdeg, m1 = sea1 / cdeg;

  float eL[2];
  if (H == 2) {
    float2 av = *(const float2*)(asrc + 2 * n);
    float2 dv = *(const float2*)(adst + 2 * n);
    #pragma unroll
    for (int h = 0; h < 2; ++h) {
      float lg = ((h == 0) ? av.x : av.y) + ((h == 0) ? dv.x : dv.y) +
                 m0 * Ae[aeoff + h] + m1 * Ae[aeoff + 2 + h];
      lg = (lg > 0.f) ? lg : NEG_SLOPE * lg;
      eL[h] = __expf(lg);
    }
  } else {
    float lg = asrc[n] + adst[n] + m0 * Ae[aeoff] + m1 * Ae[aeoff + 1];
    lg = (lg > 0.f) ? lg : NEG_SLOPE * lg;
    eL[0] = __expf(lg);
    eL[1] = 0.f;
  }

  // per-head-class denominator + self-loop term
  #pragma unroll
  for (int off = H; off < 64; off <<= 1) lsum += __shfl_xor(lsum, off);
  float tot = (H == 2) ? __shfl(lsum, hB) : lsum;
  float eSelf = (H == 2) ? eL[hB] : eL[0];
  float inv = 1.0f / (tot + eSelf + 1e-16f);

  // self-loop message: own row
  if (COLS == 4) {
    uint2 u = *(const uint2*)(xh + (size_t)n * D + 4 * t);
    acc[0][0] = fmaf(eSelf, __uint_as_float(u.x << 16), acc[0][0]);
    acc[0][1] = fmaf(eSelf, __uint_as_float(u.x & 0xFFFF0000u), acc[0][1]);
    acc[0][2] = fmaf(eSelf, __uint_as_float(u.y << 16), acc[0][2]);
    acc[0][3] = fmaf(eSelf, __uint_as_float(u.y & 0xFFFF0000u), acc[0][3]);
  } else {
    unsigned u = *(const unsigned*)(xh + (size_t)n * D + 2 * t);
    acc[0][0] = fmaf(eSelf, __uint_as_float(u << 16), acc[0][0]);
    acc[0][1] = fmaf(eSelf, __uint_as_float(u & 0xFFFF0000u), acc[0][1]);
  }

  float v[COLS];
  #pragma unroll
  for (int c = 0; c < COLS; ++c) {
    v[c] = fmaf(inv, (acc[0][c] + acc[1][c]) + (acc[2][c] + acc[3][c]),
                bias[COLS * t + c]);
    if (ACT) v[c] = (v[c] > 0.f) ? v[c] : expm1f(v[c]);
  }
  if (COLS == 4) {
    *(float4*)(out + (size_t)n * D + 4 * t) = make_float4(v[0], v[1], v[2], v[3]);
  } else {
    *(float2*)(out + (size_t)n * D + 2 * t) = make_float2(v[0], v[1]);
  }
}

// ---------- launch ----------
extern "C" void kernel_launch(void* const* d_in, const int* in_sizes, int n_in,
                              void* d_out, int out_size, void* d_ws, size_t ws_size,
                              hipStream_t stream) {
  const float* x    = (const float*)d_in[0];
  const int*   ei   = (const int*)d_in[1];
  const float* ea   = (const float*)d_in[2];
  const float* W1   = (const float*)d_in[3];
  const float* as1  = (const float*)d_in[4];
  const float* ad1  = (const float*)d_in[5];
  const float* We1  = (const float*)d_in[6];
  const float* ae1  = (const float*)d_in[7];
  const float* b1   = (const float*)d_in[8];
  const float* W2   = (const float*)d_in[9];
  const float* as2  = (const float*)d_in[10];
  const float* ad2  = (const float*)d_in[11];
  const float* We2  = (const float*)d_in[12];
  const float* ae2  = (const float*)d_in[13];
  const float* b2   = (const float*)d_in[14];
  float* out = (float*)d_out;

  char* w = (char*)d_ws;
  size_t off = 0;
  auto alloc = [&](size_t bytes) -> void* {
    void* p = w + off;
    off = (off + bytes + 255) & ~(size_t)255;
    return p;
  };
  unsigned short* xhb   = (unsigned short*)alloc((size_t)N_NODES * 256 * 2);
  float*          hbuf  = (float*)alloc((size_t)N_NODES * 256 * 4);
  unsigned short* B1hi  = (unsigned short*)alloc(256 * 256 * 2);
  unsigned short* B1lo  = (unsigned short*)alloc(256 * 256 * 2);
  unsigned short* B2hi  = (unsigned short*)alloc(128 * 256 * 2);
  unsigned short* B2lo  = (unsigned short*)alloc(128 * 256 * 2);
  int*      rowptr   = (int*)alloc((N_NODES + 1) * 4);
  int*      cnt      = (int*)alloc(N_NODES * 4);
  int*      cnt8     = (int*)alloc((size_t)N_NODES * 8 * 4);
  int*      rank     = (int*)alloc((size_t)N_EDGES * 4);
  int*      bsum     = (int*)alloc(256 * 4);
  uint2*    ecsr     = (uint2*)alloc((size_t)EP * 8);
  float*    asrc     = (float*)alloc(N_NODES * 2 * 4);
  float*    adst     = (float*)alloc(N_NODES * 2 * 4);
  float*    Ae       = (float*)alloc(16 * 4);

  auto cdiv = [](int a, int b) { return (a + b - 1) / b; };

  // stage 1: input-only prep (zero cnt8 | W^T splits | Ae)
  prep_inputs<<<FILLB + 384 + 6, 256, 0, stream>>>(cnt8, W1, W2, B1hi, B1lo, B2hi, B2lo,
                                                   ae1, ae2, We1, We2, Ae);
  // stage 2: conv1 GEMM overlapped with edge rank pass (independent chains)
  gemm1_rank<<<GEMM1B + RANKB, 256, 0, stream>>>(x, B1hi, B1lo, xhb, as1, ad1, asrc, adst,
                                                 ei, cnt8, rank);
  // stage 3-5: CSR build
  combine_bsum<<<SCAN_BLOCKS, 256, 0, stream>>>(cnt8, cnt, bsum);
  emit_rowptr<<<SCAN_BLOCKS, 256, 0, stream>>>(cnt, bsum, rowptr);
  scatter_pass<<<RANKB, 256, 0, stream>>>(ei, ea, rowptr, rank, cnt8, ecsr);

  // conv1 aggregate (implicit self-loop) -> hbuf
  aggregate_fused<2, 1><<<N_NODES, 64, 0, stream>>>(xhb, asrc, adst, ecsr, rowptr,
                                                    Ae, 0, b1, hbuf);
  // conv2
  gemm_split1<<<dim3(1, cdiv(N_NODES, 64)), 256, 0, stream>>>(hbuf, B2hi, B2lo, xhb, N_NODES, 128,
                                                              as2, ad2, asrc, adst);
  aggregate_fused<1, 0><<<N_NODES, 64, 0, stream>>>(xhb, asrc, adst, ecsr, rowptr,
                                                    Ae, 4, b2, out);
}